// Round 1
// baseline (48.798 us; speedup 1.0000x reference)
//
#include <hip/hip_runtime.h>

// Problem constants (match reference)
#define BB 32
#define DD 32
#define HH 256
#define WW 256
#define KK 512
#define NSLICE 16           // k-slices per image (kernel B grid.x)
#define ROWS 32             // k-rows per slice; NSLICE*ROWS == KK

// ---------------------------------------------------------------------------
// Kernel A: gather pred[b][k][0..31] from ebd at keypoints, plus sum(x^2).
// One thread per (b,k) column. Writes columns contiguously (32 f32 = 128B).
// ---------------------------------------------------------------------------
__global__ __launch_bounds__(256) void tagloss_gather(
    const float* __restrict__ ebd, const int* __restrict__ kpts,
    float* __restrict__ wsP, float* __restrict__ wsS) {
  int gid = blockIdx.x * 256 + threadIdx.x;   // 0 .. BB*KK-1 ; b = gid>>9
  int b = gid >> 9;
  int y = kpts[gid * 2 + 0];
  int x = kpts[gid * 2 + 1];
  const float* src = ebd + (size_t)b * DD * HH * WW + (size_t)y * WW + x;

  float v[DD];
  float ssq = 0.f;
#pragma unroll
  for (int d = 0; d < DD; ++d) {
    v[d] = src[(size_t)d * HH * WW];
    ssq = fmaf(v[d], v[d], ssq);
  }
  float4* dst = (float4*)(wsP + (size_t)gid * DD);
#pragma unroll
  for (int c = 0; c < DD / 4; ++c)
    dst[c] = make_float4(v[4 * c + 0], v[4 * c + 1], v[4 * c + 2], v[4 * c + 3]);
  wsS[gid] = ssq;
}

// ---------------------------------------------------------------------------
// Kernel B: per (image, k-slice of 32 rows) block. Stage all 512 columns of
// the image into LDS (XOR-swizzled float4 chunks: physical chunk =
// c ^ ((l>>2)&7) -> inner-loop ds_read_b128 spreads over all 8 bank groups).
// Each thread computes a 4x4 tile of dots over d=32, then the sigmoid-MSE
// epilogue; block partial -> atomicAdd.
// ---------------------------------------------------------------------------
__global__ __launch_bounds__(256) void tagloss_pairs(
    const float* __restrict__ wsP, const float* __restrict__ wsS,
    const int* __restrict__ tags, float* __restrict__ out) {
  __shared__ float4 predL[KK * 8];   // 64 KiB, swizzled
  __shared__ float  ssqL[KK];        // 2 KiB
  __shared__ int    tagL[KK];        // 2 KiB
  __shared__ float  red[4];

  const int tid = threadIdx.x;
  const int b = blockIdx.y;
  const int slice = blockIdx.x;

  // ---- stage ----
  const float4* src = (const float4*)(wsP + (size_t)b * KK * DD);
#pragma unroll
  for (int i = 0; i < 16; ++i) {
    int j = tid + i * 256;            // 0..4095 float4s
    int l = j >> 3;
    int c = j & 7;
    predL[l * 8 + (c ^ ((l >> 2) & 7))] = src[j];
  }
  ssqL[tid]       = wsS[b * KK + tid];
  ssqL[tid + 256] = wsS[b * KK + tid + 256];
  tagL[tid]       = tags[b * KK + tid];
  tagL[tid + 256] = tags[b * KK + tid + 256];
  __syncthreads();

  // ---- compute ----
  const int kt  = tid >> 5;           // 0..7  (k-tile within slice)
  const int lt0 = tid & 31;           // l-tile phase
  const int krow0 = slice * ROWS + kt * 4;

  float ssqk[4];
  int   tagk[4];
#pragma unroll
  for (int j = 0; j < 4; ++j) {
    ssqk[j] = ssqL[krow0 + j];
    tagk[j] = tagL[krow0 + j];
  }

  float acc = 0.f;
  for (int m = 0; m < 4; ++m) {
    const int lt = lt0 + 32 * m;      // 0..127
    const int l0 = lt * 4;
    const int sl = lt0 & 7;           // swizzle key for l-columns

    float dot[4][4];
#pragma unroll
    for (int j = 0; j < 4; ++j)
#pragma unroll
      for (int i = 0; i < 4; ++i) dot[j][i] = 0.f;

    float4 Areg[4], Breg[4];
#pragma unroll
    for (int c = 0; c < 8; ++c) {
#pragma unroll
      for (int j = 0; j < 4; ++j) Areg[j] = predL[(krow0 + j) * 8 + (c ^ kt)];
#pragma unroll
      for (int i = 0; i < 4; ++i) Breg[i] = predL[(l0 + i) * 8 + (c ^ sl)];
#pragma unroll
      for (int j = 0; j < 4; ++j)
#pragma unroll
        for (int i = 0; i < 4; ++i) {
          dot[j][i] = fmaf(Areg[j].x, Breg[i].x, dot[j][i]);
          dot[j][i] = fmaf(Areg[j].y, Breg[i].y, dot[j][i]);
          dot[j][i] = fmaf(Areg[j].z, Breg[i].z, dot[j][i]);
          dot[j][i] = fmaf(Areg[j].w, Breg[i].w, dot[j][i]);
        }
    }

    // epilogue: expo = (ssq_k + ssq_l - 2*dot)/32 ; ps = 2/(1+exp(expo))
#pragma unroll
    for (int j = 0; j < 4; ++j) {
#pragma unroll
      for (int i = 0; i < 4; ++i) {
        float expo = (ssqk[j] + ssqL[l0 + i] - 2.f * dot[j][i]) * (1.f / 32.f);
        float ps = 2.f / (1.f + __expf(expo));
        float t = (tagk[j] == tagL[l0 + i]) ? 1.f : 0.f;
        float df = t - ps;
        acc = fmaf(df, df, acc);
      }
    }
  }

  // ---- reduce ----
#pragma unroll
  for (int off = 32; off > 0; off >>= 1) acc += __shfl_down(acc, off);
  if ((tid & 63) == 0) red[tid >> 6] = acc;
  __syncthreads();
  if (tid == 0) {
    float s = red[0] + red[1] + red[2] + red[3];
    atomicAdd(out, s * (1.f / 8388608.f));  // / (B*K*K) = 2^-23, exact
  }
}

extern "C" void kernel_launch(void* const* d_in, const int* in_sizes, int n_in,
                              void* d_out, int out_size, void* d_ws, size_t ws_size,
                              hipStream_t stream) {
  const float* ebd  = (const float*)d_in[0];
  const int*   kpts = (const int*)d_in[1];
  const int*   tags = (const int*)d_in[2];
  float* out = (float*)d_out;

  float* wsP = (float*)d_ws;                       // BB*KK*DD f32 = 2 MiB
  float* wsS = wsP + (size_t)BB * KK * DD;         // BB*KK f32 = 64 KiB

  hipMemsetAsync(d_out, 0, sizeof(float), stream);
  tagloss_gather<<<(BB * KK) / 256, 256, 0, stream>>>(ebd, kpts, wsP, wsS);
  tagloss_pairs<<<dim3(NSLICE, BB), 256, 0, stream>>>(wsP, wsS, tags, out);
}

// Round 2
// 36.656 us; speedup vs baseline: 1.3312x; 1.3312x over previous
//
#include <hip/hip_runtime.h>

// Problem constants (match reference)
#define BB 32
#define DD 32
#define HH 256
#define WW 256
#define KK 512
#define NSLICE 16           // k-slices per image (kernel B grid.x)
#define ROWS 32             // k-rows per slice; NSLICE*ROWS == KK

// ---------------------------------------------------------------------------
// Kernel A: gather pred[b][k][d] with one thread per (col=b*K+k, d).
// 2048 blocks x 256 threads -> every CU issues scatter loads in parallel.
// ssq per column via shfl_xor reduction over the 32-lane d-group.
// Writes wsP[col][d] coalesced (each wave writes 2 contiguous 128B columns).
// ---------------------------------------------------------------------------
__global__ __launch_bounds__(256) void tagloss_gather(
    const float* __restrict__ ebd, const int* __restrict__ kpts,
    float* __restrict__ wsP, float* __restrict__ wsS) {
  int gid = blockIdx.x * 256 + threadIdx.x;   // 0 .. BB*KK*DD-1
  int col = gid >> 5;                         // 0 .. BB*KK-1
  int d   = gid & 31;
  int b   = col >> 9;

  int y = kpts[col * 2 + 0];
  int x = kpts[col * 2 + 1];
  float v = ebd[((size_t)(b * DD + d)) * (HH * WW) + (size_t)y * WW + x];

  wsP[(size_t)col * DD + d] = v;

  float s = v * v;
#pragma unroll
  for (int m = 16; m > 0; m >>= 1) s += __shfl_xor(s, m);
  if (d == 0) wsS[col] = s;
}

// ---------------------------------------------------------------------------
// Kernel B: block = (image, slice of 32 k-rows). Stage all 512 columns of the
// image into LDS (float4 chunks, physical chunk = c ^ ((col>>3)&7)).
// Wave w (tid>>6) owns 8 k-rows -> A-reads are wave-uniform broadcasts.
// Lane owns 8 l-columns -> B-reads: 8 consecutive lanes span 128B (32 banks).
// 8x8 register tile of dots (2048 FMA / 64 b128 reads), sigmoid-MSE epilogue,
// wave reduce, one atomicAdd per block.
// ---------------------------------------------------------------------------
__global__ __launch_bounds__(256, 2) void tagloss_pairs(
    const float* __restrict__ wsP, const float* __restrict__ wsS,
    const int* __restrict__ tags, float* __restrict__ out) {
  __shared__ float4 predL[KK * 8];   // 64 KiB, swizzled chunks
  __shared__ float  ssqL[KK];        // 2 KiB
  __shared__ int    tagL[KK];        // 2 KiB
  __shared__ float  red[4];

  const int tid = threadIdx.x;
  const int b = blockIdx.y;
  const int slice = blockIdx.x;

  // ---- stage ----
  const float4* src = (const float4*)(wsP + (size_t)b * KK * DD);
#pragma unroll
  for (int i = 0; i < 16; ++i) {
    int j = tid + i * 256;            // 0..4095 float4s; col = j>>3, chunk = j&7
    int l = j >> 3;
    int c = j & 7;
    predL[l * 8 + (c ^ ((l >> 3) & 7))] = src[j];
  }
  ssqL[tid]       = wsS[b * KK + tid];
  ssqL[tid + 256] = wsS[b * KK + tid + 256];
  tagL[tid]       = tags[b * KK + tid];
  tagL[tid + 256] = tags[b * KK + tid + 256];
  __syncthreads();

  // ---- compute: wave owns 8 k-rows, lane owns 8 l-cols ----
  const int wave = tid >> 6;                 // 0..3
  const int lane = tid & 63;                 // 0..63
  const int krow0 = slice * ROWS + wave * 8; // multiple of 8
  const int l0 = lane * 8;
  const int sA = (krow0 >> 3) & 7;           // uniform per wave
  const int sB = lane & 7;

  float dot[8][8];
#pragma unroll
  for (int j = 0; j < 8; ++j)
#pragma unroll
    for (int i = 0; i < 8; ++i) dot[j][i] = 0.f;

#pragma unroll
  for (int c = 0; c < 8; ++c) {
    float4 Areg[8], Breg[8];
#pragma unroll
    for (int j = 0; j < 8; ++j) Areg[j] = predL[(krow0 + j) * 8 + (c ^ sA)];
#pragma unroll
    for (int i = 0; i < 8; ++i) Breg[i] = predL[(l0 + i) * 8 + (c ^ sB)];
#pragma unroll
    for (int j = 0; j < 8; ++j)
#pragma unroll
      for (int i = 0; i < 8; ++i) {
        dot[j][i] = fmaf(Areg[j].x, Breg[i].x, dot[j][i]);
        dot[j][i] = fmaf(Areg[j].y, Breg[i].y, dot[j][i]);
        dot[j][i] = fmaf(Areg[j].z, Breg[i].z, dot[j][i]);
        dot[j][i] = fmaf(Areg[j].w, Breg[i].w, dot[j][i]);
      }
  }

  // ---- epilogue ----
  float ssqk[8];
  int   tagk[8];
#pragma unroll
  for (int j = 0; j < 8; ++j) {
    ssqk[j] = ssqL[krow0 + j];
    tagk[j] = tagL[krow0 + j];
  }
  float4 sb0 = ((const float4*)ssqL)[lane * 2 + 0];
  float4 sb1 = ((const float4*)ssqL)[lane * 2 + 1];
  int4   tb0 = ((const int4*)tagL)[lane * 2 + 0];
  int4   tb1 = ((const int4*)tagL)[lane * 2 + 1];
  float ssqb[8] = {sb0.x, sb0.y, sb0.z, sb0.w, sb1.x, sb1.y, sb1.z, sb1.w};
  int   tagb[8] = {tb0.x, tb0.y, tb0.z, tb0.w, tb1.x, tb1.y, tb1.z, tb1.w};

  float acc = 0.f;
#pragma unroll
  for (int j = 0; j < 8; ++j) {
#pragma unroll
    for (int i = 0; i < 8; ++i) {
      float expo = (ssqk[j] + ssqb[i] - 2.f * dot[j][i]) * (1.f / 32.f);
      float ps = 2.f * __builtin_amdgcn_rcpf(1.f + __expf(expo));
      float t = (tagk[j] == tagb[i]) ? 1.f : 0.f;
      float df = t - ps;
      acc = fmaf(df, df, acc);
    }
  }

  // ---- reduce ----
#pragma unroll
  for (int off = 32; off > 0; off >>= 1) acc += __shfl_down(acc, off);
  if (lane == 0) red[wave] = acc;
  __syncthreads();
  if (tid == 0) {
    float s = red[0] + red[1] + red[2] + red[3];
    atomicAdd(out, s * (1.f / 8388608.f));  // / (B*K*K) = 2^-23, exact
  }
}

extern "C" void kernel_launch(void* const* d_in, const int* in_sizes, int n_in,
                              void* d_out, int out_size, void* d_ws, size_t ws_size,
                              hipStream_t stream) {
  const float* ebd  = (const float*)d_in[0];
  const int*   kpts = (const int*)d_in[1];
  const int*   tags = (const int*)d_in[2];
  float* out = (float*)d_out;

  float* wsP = (float*)d_ws;                       // BB*KK*DD f32 = 2 MiB
  float* wsS = wsP + (size_t)BB * KK * DD;         // BB*KK f32 = 64 KiB

  hipMemsetAsync(d_out, 0, sizeof(float), stream);
  tagloss_gather<<<(BB * KK * DD) / 256, 256, 0, stream>>>(ebd, kpts, wsP, wsS);
  tagloss_pairs<<<dim3(NSLICE, BB), 256, 0, stream>>>(wsP, wsS, tags, out);
}

// Round 3
// 27.943 us; speedup vs baseline: 1.7464x; 1.3118x over previous
//
#include <hip/hip_runtime.h>

// Problem constants (match reference)
#define BB 32
#define DD 32
#define HH 256
#define WW 256
#define KK 512

typedef __attribute__((ext_vector_type(8))) short bf16x8;
typedef __attribute__((ext_vector_type(4))) float f32x4;

// ws layout (bytes): [0,1MB) bf16-hi ushort[16384*32]; [1MB,2MB) bf16-lo; [2MB,+64KB) ssq f32
#define LO_OFF  (1u << 20)
#define SSQ_OFF (2u << 20)

// ---------------------------------------------------------------------------
// Kernel A: gather pred[b][k][d], split into bf16 hi/lo planes (hi = RN-bf16(v),
// lo = RN-bf16(v - hi); v - hi is exact in f32). ssq computed from exact f32 v.
// One thread per (col,d); also zeroes out[0] (pairs runs strictly after).
// ---------------------------------------------------------------------------
__global__ __launch_bounds__(256) void tagloss_gather(
    const float* __restrict__ ebd, const int* __restrict__ kpts,
    char* __restrict__ ws, float* __restrict__ out) {
  int gid = blockIdx.x * 256 + threadIdx.x;   // 0 .. BB*KK*DD-1
  if (gid == 0) out[0] = 0.f;
  int col = gid >> 5;                         // 0 .. BB*KK-1
  int d   = gid & 31;
  int b   = col >> 9;

  int y = kpts[col * 2 + 0];
  int x = kpts[col * 2 + 1];
  float v = ebd[((size_t)(b * DD + d)) * (HH * WW) + (size_t)y * WW + x];

  unsigned u  = __float_as_uint(v);
  unsigned rn = u + 0x7FFFu + ((u >> 16) & 1u);        // RN-to-bf16 (ties-even)
  float hif = __uint_as_float(rn & 0xFFFF0000u);
  float lof = v - hif;                                  // exact
  unsigned ul = __float_as_uint(lof);
  unsigned rl = ul + 0x7FFFu + ((ul >> 16) & 1u);

  ((ushort*)ws)[col * DD + d]            = (ushort)(rn >> 16);
  ((ushort*)(ws + LO_OFF))[col * DD + d] = (ushort)(rl >> 16);

  float s = v * v;
#pragma unroll
  for (int m = 16; m > 0; m >>= 1) s += __shfl_xor(s, m);
  if (d == 0) ((float*)(ws + SSQ_OFF))[col] = s;
}

// ---------------------------------------------------------------------------
// Kernel B: block = (slice of 32 k-rows, image). Stage hi/lo planes of all 512
// columns into LDS as 16B chunks, swizzled: phys_chunk = dc ^ ((col>>1)&3)
// -> every 8-lane b128 group covers all 32 banks exactly once.
// Wave w: ktile = w&1 (A-frag hoisted), ltiles (w>>1)*16..+15. Per ltile:
// 3 chained mfma_f32_16x16x32_bf16 (ah*bh + ah*bl + al*bh), then the
// sigmoid-MSE epilogue on the 4 C-regs (row = (lane>>4)*4+reg, col = lane&15).
// ---------------------------------------------------------------------------
__global__ __launch_bounds__(256, 2) void tagloss_pairs(
    const char* __restrict__ ws, const int* __restrict__ tags,
    float* __restrict__ out) {
  __shared__ __align__(16) char P[65536];   // [plane 32KB][col*64 + swz_chunk*16]
  __shared__ float ssqL[KK];
  __shared__ int   tagL[KK];
  __shared__ float red[4];

  const int tid = threadIdx.x;
  const int b = blockIdx.y;
  const int slice = blockIdx.x;

  // ---- stage: 4096 16B chunks (hi then lo plane) ----
#pragma unroll
  for (int i = 0; i < 16; ++i) {
    int j = tid + i * 256;            // 0..4095
    int plane = j >> 11;              // 0 = hi, 1 = lo
    int col = (j >> 2) & 511;
    int dc = j & 3;
    const float4* src = (const float4*)(ws + (size_t)plane * LO_OFF +
                                        (size_t)b * 32768 + col * 64 + dc * 16);
    *(float4*)(P + plane * 32768 + col * 64 + ((dc ^ ((col >> 1) & 3)) * 16)) = *src;
  }
  ssqL[tid]       = ((const float*)(ws + SSQ_OFF))[b * KK + tid];
  ssqL[tid + 256] = ((const float*)(ws + SSQ_OFF))[b * KK + tid + 256];
  tagL[tid]       = tags[b * KK + tid];
  tagL[tid + 256] = tags[b * KK + tid + 256];
  __syncthreads();

  // ---- compute ----
  const int w = tid >> 6, lane = tid & 63;
  const int lx = lane & 15, dchunk = lane >> 4;

  const int colA = slice * 32 + (w & 1) * 16 + lx;      // A column (k-point)
  const int swzA = ((dchunk ^ ((colA >> 1) & 3)) * 16);
  bf16x8 ahi = *(const bf16x8*)(P + colA * 64 + swzA);
  bf16x8 alo = *(const bf16x8*)(P + 32768 + colA * 64 + swzA);

  const int krow = slice * 32 + (w & 1) * 16 + dchunk * 4;  // C rows for this lane
  float ssqk[4];
  int   tagk[4];
#pragma unroll
  for (int r = 0; r < 4; ++r) { ssqk[r] = ssqL[krow + r]; tagk[r] = tagL[krow + r]; }

  float loss = 0.f;
  const int lt0 = (w >> 1) * 16;
#pragma unroll 4
  for (int q = 0; q < 16; ++q) {
    const int colB = (lt0 + q) * 16 + lx;               // B column (l-point)
    const int swzB = ((dchunk ^ ((colB >> 1) & 3)) * 16);
    bf16x8 bhi = *(const bf16x8*)(P + colB * 64 + swzB);
    bf16x8 blo = *(const bf16x8*)(P + 32768 + colB * 64 + swzB);

    f32x4 acc = {0.f, 0.f, 0.f, 0.f};
    acc = __builtin_amdgcn_mfma_f32_16x16x32_bf16(alo, bhi, acc, 0, 0, 0);
    acc = __builtin_amdgcn_mfma_f32_16x16x32_bf16(ahi, blo, acc, 0, 0, 0);
    acc = __builtin_amdgcn_mfma_f32_16x16x32_bf16(ahi, bhi, acc, 0, 0, 0);

    float ssql = ssqL[colB];
    int   tagl = tagL[colB];
#pragma unroll
    for (int r = 0; r < 4; ++r) {
      float expo = (ssqk[r] + ssql - 2.f * acc[r]) * 0.03125f;
      float ps = 2.f * __builtin_amdgcn_rcpf(1.f + __expf(expo));
      float t = (tagk[r] == tagl) ? 1.f : 0.f;
      float df = t - ps;
      loss = fmaf(df, df, loss);
    }
  }

  // ---- reduce ----
#pragma unroll
  for (int off = 32; off > 0; off >>= 1) loss += __shfl_down(loss, off);
  if (lane == 0) red[w] = loss;
  __syncthreads();
  if (tid == 0)
    atomicAdd(out, (red[0] + red[1] + red[2] + red[3]) * (1.f / 8388608.f));
}

extern "C" void kernel_launch(void* const* d_in, const int* in_sizes, int n_in,
                              void* d_out, int out_size, void* d_ws, size_t ws_size,
                              hipStream_t stream) {
  const float* ebd  = (const float*)d_in[0];
  const int*   kpts = (const int*)d_in[1];
  const int*   tags = (const int*)d_in[2];
  float* out = (float*)d_out;

  tagloss_gather<<<(BB * KK * DD) / 256, 256, 0, stream>>>(ebd, kpts, (char*)d_ws, out);
  tagloss_pairs<<<dim3(16, BB), 256, 0, stream>>>((const char*)d_ws, tags, out);
}